// Round 3
// baseline (725.430 us; speedup 1.0000x reference)
//
#include <hip/hip_runtime.h>
#include <hip/hip_bf16.h>

// Round 3: all-f32 implementation (inputs f32 confirmed round 2; output f32
// per reference dtype). Structure: pair_first = repeat(arange(N),32) -> dense
// 32-neighbor segments. 13 launches: setup, f0, 5 x (xt, envlstm).

#define DEG 32
#define NA 4096        // atoms
#define NP 131072      // pairs
#define NS 20
#define NF1C 20
#define NF0C 40
#define NGC 80

typedef __hip_bfloat16 bf16;

__device__ __forceinline__ float sigmoidf_(float x){ return 1.f/(1.f+expf(-x)); }
__device__ __forceinline__ float softplusf_(float x){ return fmaxf(x,0.f) + log1pf(expf(-fabsf(x))); }
// mu_s = linspace(1/5, 1/0.7, 20); sigma = (1/0.7-1/5)/20
__device__ __forceinline__ float senseval(float ivd, float cu, int s){
  float mu = 0.2f + (float)s * 0.06466165413533835f;   // step = (1/0.7-0.2)/19
  float z  = (ivd - mu) * 16.27906976744186f;          // 1/sigma
  return expf(-0.5f*z*z) * cu;
}

// ---------------- setup: pair geometry, atom encodings, W transposes ---------
__global__ __launch_bounds__(256) void k_setup(
    const int* __restrict__ pf, const int* __restrict__ ps,
    const int* __restrict__ species,
    const float* __restrict__ coord, const float* __restrict__ xh,
    const float* __restrict__ pw0, const float* __restrict__ pb1,
    const float* __restrict__ Wint, const float* __restrict__ Wself,
    float* __restrict__ invd, float* __restrict__ cut,
    float* __restrict__ indf, float* __restrict__ proj0,
    float* __restrict__ WtF, float* __restrict__ WsT)
{
  int tid = blockIdx.x*256 + threadIdx.x;
  if (tid < NP){
    int i = pf[tid], j = ps[tid];
    float dx = coord[i*3+0]-coord[j*3+0];
    float dy = coord[i*3+1]-coord[j*3+1];
    float dz = coord[i*3+2]-coord[j*3+2];
    float d = sqrtf(dx*dx+dy*dy+dz*dz + 1e-12f);
    invd[tid] = 1.f/d;
    float cu = 0.f;
    if (d < 7.5f){ float c = cosf(d * 0.20943951023931953f); cu = c*c; } // pi/15
    cut[tid] = cu;
  }
  if (tid < NA){
    int sp = species[tid];
    float f0 = (sp==1)?1.f:0.f, f1 = (sp==8)?1.f:0.f;
    float f2=xh[tid*3+0], f3=xh[tid*3+1], f4=xh[tid*3+2];
    indf[tid*5+0]=f0; indf[tid*5+1]=f1; indf[tid*5+2]=f2; indf[tid*5+3]=f3; indf[tid*5+4]=f4;
    proj0[tid] = pb1[0] + f0*pw0[0] + f1*pw0[1] + f2*pw0[2] + f3*pw0[3] + f4*pw0[4];
  }
  if (tid < NGC*800){ int g = tid/800, e = tid%800; WtF[tid] = Wint[e*NGC+g]; }
  if (tid < NGC*NF0C){ int g = tid/NF0C, f = tid%NF0C; WsT[tid] = Wself[f*NGC+g]; }
}

// ---------------- f0 = hipnn(ind_f) -> c_t, h_t -------------------------------
__global__ __launch_bounds__(256) void k_f0(
    const int* __restrict__ ps,
    const float* __restrict__ invd, const float* __restrict__ cut,
    const float* __restrict__ indf,
    const float* __restrict__ intw, const float* __restrict__ selfw,
    const float* __restrict__ selfb,
    const float* __restrict__ aw, const float* __restrict__ ab,
    float* __restrict__ ct, float* __restrict__ hout)
{
  __shared__ float xn[4][160];
  __shared__ float env[4][100];
  __shared__ float ya[4][40];
  __shared__ float yb[4][40];
  int a_loc = threadIdx.x>>6, slot = threadIdx.x&63;
  int atom = blockIdx.x*4 + a_loc;
  int p0 = atom*DEG;
  for(int idx=slot; idx<160; idx+=64){
    int k = idx/5, f = idx%5;
    int n = ps[p0+k];
    xn[a_loc][idx] = indf[n*5+f];
  }
  __syncthreads();
  for(int e=slot; e<100; e+=64){
    int s = e/5, f = e%5;
    float acc=0.f;
    for(int k=0;k<DEG;k++){
      float sv = senseval(invd[p0+k], cut[p0+k], s);
      acc += sv * xn[a_loc][k*5+f];
    }
    env[a_loc][e]=acc;
  }
  __syncthreads();
  if (slot < 40){
    int o = slot;
    float acc = selfb[o];
    #pragma unroll
    for(int f=0;f<5;f++) acc += indf[atom*5+f]*selfw[f*40+o];
    for(int e=0;e<100;e++) acc += env[a_loc][e]*intw[e*40+o];
    ya[a_loc][o] = softplusf_(acc);
  }
  __syncthreads();
  float* cur = ya[a_loc]; float* nxt = yb[a_loc];
  for(int l=0;l<3;l++){
    if (slot<40){
      int o=slot;
      float acc = ab[l*40+o];
      for(int f=0;f<40;f++) acc += cur[f]*aw[l*1600+f*40+o];
      nxt[o] = softplusf_(acc);
    }
    __syncthreads();
    float* t=cur; cur=nxt; nxt=t;
  }
  if (slot<20){
    ct[atom*20+slot]   = cur[slot];
    hout[atom*20+slot] = cur[20+slot];
  }
}

// ---------------- x_t = hipnn_h1(x_in) (scalar input) -------------------------
__global__ __launch_bounds__(256) void k_xt(
    const int* __restrict__ ps,
    const float* __restrict__ invd, const float* __restrict__ cut,
    const float* __restrict__ xraw, const float* __restrict__ x0,
    int use_raw, int col,
    const float* __restrict__ intw, const float* __restrict__ selfw,
    const float* __restrict__ selfb,
    const float* __restrict__ aw, const float* __restrict__ ab,
    float* __restrict__ xt)
{
  __shared__ float xv[8][32];
  __shared__ float env1[8][20];
  __shared__ float ya[8][20];
  __shared__ float yb[8][20];
  int a_loc = threadIdx.x>>5, slot = threadIdx.x&31;
  int atom = blockIdx.x*8 + a_loc;
  int p0 = atom*DEG;
  {
    int n = ps[p0+slot];
    xv[a_loc][slot] = use_raw ? xraw[n*2+col] : x0[n];
  }
  __syncthreads();
  if (slot<20){
    int s=slot; float acc=0.f;
    for(int k=0;k<DEG;k++) acc += senseval(invd[p0+k],cut[p0+k],s) * xv[a_loc][k];
    env1[a_loc][s]=acc;
  }
  __syncthreads();
  if (slot<20){
    int o=slot;
    float xs = use_raw ? xraw[atom*2+col] : x0[atom];
    float acc = selfb[o] + xs*selfw[o];
    #pragma unroll
    for(int s=0;s<20;s++) acc += env1[a_loc][s]*intw[s*20+o];
    ya[a_loc][o]=softplusf_(acc);
  }
  __syncthreads();
  float* cur = ya[a_loc]; float* nxt = yb[a_loc];
  for(int l=0;l<3;l++){
    if(slot<20){
      int o=slot;
      float acc = ab[l*20+o];
      #pragma unroll
      for(int f=0;f<20;f++) acc += cur[f]*aw[l*400+f*20+o];
      nxt[o]=softplusf_(acc);
    }
    __syncthreads();
    float* t=cur;cur=nxt;nxt=t;
  }
  if(slot<20) xt[atom*20+slot]=cur[slot];
}

// ---------------- env(20x40) + GEMM(800->80) + LSTM epilogue ------------------
__global__ __launch_bounds__(320) void k_envlstm(
    const int* __restrict__ ps,
    const float* __restrict__ invd, const float* __restrict__ cut,
    const float* __restrict__ xt, const float* __restrict__ hin,
    const float* __restrict__ WtF, const float* __restrict__ WsT,
    const float* __restrict__ Wb, const float* __restrict__ pw1,
    const float* __restrict__ proj0,
    float* __restrict__ ct, float* __restrict__ hout, float* __restrict__ x0,
    float* __restrict__ outp, int out_col)
{
  __shared__ float env_s[16*800];
  __shared__ float tmp_s[16*80];
  __shared__ float red_s[16*20];
  int t = threadIdx.x;
  int a_loc = t/20, s = t%20;
  int atom = blockIdx.x*16 + a_loc;
  int p0 = atom*DEG;
  // P1: env[s][0..39] per (atom, s) thread
  {
    float acc[40];
    #pragma unroll
    for(int q=0;q<40;q++) acc[q]=0.f;
    for(int k=0;k<DEG;k++){
      int p=p0+k;
      float sv = senseval(invd[p],cut[p],s);
      int n = ps[p];
      const float4* xr = reinterpret_cast<const float4*>(xt + n*20);
      const float4* hr = reinterpret_cast<const float4*>(hin + n*20);
      #pragma unroll
      for(int q=0;q<5;q++){
        float4 v = xr[q];
        acc[4*q+0] += sv*v.x; acc[4*q+1] += sv*v.y; acc[4*q+2] += sv*v.z; acc[4*q+3] += sv*v.w;
      }
      #pragma unroll
      for(int q=0;q<5;q++){
        float4 v = hr[q];
        acc[20+4*q+0] += sv*v.x; acc[20+4*q+1] += sv*v.y; acc[20+4*q+2] += sv*v.z; acc[20+4*q+3] += sv*v.w;
      }
    }
    float4* erow = reinterpret_cast<float4*>(env_s + a_loc*800 + s*40);
    #pragma unroll
    for(int q=0;q<10;q++) erow[q] = make_float4(acc[4*q],acc[4*q+1],acc[4*q+2],acc[4*q+3]);
  }
  __syncthreads();
  // P2: tmp[g] = env.W + cat(x,h).Wself + b  (4 g's per thread)
  {
    int g0=s, g1=s+20, g2=s+40, g3=s+60;
    float a0=Wb[g0], a1=Wb[g1], a2=Wb[g2], a3=Wb[g3];
    const float* xrow = xt + atom*20;
    const float* hrow = hin + atom*20;
    #pragma unroll
    for(int f=0;f<20;f++){
      float xf = xrow[f];
      a0 += xf*WsT[g0*40+f]; a1 += xf*WsT[g1*40+f]; a2 += xf*WsT[g2*40+f]; a3 += xf*WsT[g3*40+f];
    }
    #pragma unroll
    for(int f=0;f<20;f++){
      float hf = hrow[f];
      a0 += hf*WsT[g0*40+20+f]; a1 += hf*WsT[g1*40+20+f]; a2 += hf*WsT[g2*40+20+f]; a3 += hf*WsT[g3*40+20+f];
    }
    const float4* ev = reinterpret_cast<const float4*>(env_s + a_loc*800);
    const float4* w0 = reinterpret_cast<const float4*>(WtF + g0*800);
    const float4* w1 = reinterpret_cast<const float4*>(WtF + g1*800);
    const float4* w2 = reinterpret_cast<const float4*>(WtF + g2*800);
    const float4* w3 = reinterpret_cast<const float4*>(WtF + g3*800);
    for(int e4=0;e4<200;e4++){
      float4 e = ev[e4];
      float4 q;
      q = w0[e4]; a0 += e.x*q.x + e.y*q.y + e.z*q.z + e.w*q.w;
      q = w1[e4]; a1 += e.x*q.x + e.y*q.y + e.z*q.z + e.w*q.w;
      q = w2[e4]; a2 += e.x*q.x + e.y*q.y + e.z*q.z + e.w*q.w;
      q = w3[e4]; a3 += e.x*q.x + e.y*q.y + e.z*q.z + e.w*q.w;
    }
    tmp_s[a_loc*80+g0]=a0; tmp_s[a_loc*80+g1]=a1; tmp_s[a_loc*80+g2]=a2; tmp_s[a_loc*80+g3]=a3;
  }
  __syncthreads();
  // LSTM: tmp.reshape(20,4): c = sig(t1)*c + sig(t0)*tanh(t2); h = sig(t3)*tanh(c)
  {
    int u = s;
    const float4 tv = *reinterpret_cast<const float4*>(tmp_s + a_loc*80 + u*4);
    float cold = ct[atom*20+u];
    float cnew = sigmoidf_(tv.y)*cold + sigmoidf_(tv.x)*tanhf(tv.z);
    float og   = sigmoidf_(tv.w);
    float hnew = og*tanhf(cnew);
    ct[atom*20+u]=cnew;
    hout[atom*20+u]=hnew;
    red_s[a_loc*20+u] = og*pw1[u];
  }
  __syncthreads();
  if (s==0){
    float acc = proj0[atom];
    #pragma unroll
    for(int u=0;u<20;u++) acc += red_s[a_loc*20+u];
    x0[atom]=acc;
    if(out_col>=0) outp[atom*3+out_col] = acc;
  }
}

extern "C" void kernel_launch(void* const* d_in, const int* in_sizes, int n_in,
                              void* d_out, int out_size, void* d_ws, size_t ws_size,
                              hipStream_t stream)
{
  const int*   species = (const int*)  d_in[0];
  const float* coord   = (const float*)d_in[1];
  const float* xh      = (const float*)d_in[2];
  const float* xraw    = (const float*)d_in[3];
  const int*   pf      = (const int*)  d_in[4];
  const int*   ps      = (const int*)  d_in[5];
  const float* h0_intw = (const float*)d_in[6];
  const float* h0_sw   = (const float*)d_in[7];
  const float* h0_sb   = (const float*)d_in[8];
  const float* h0_aw   = (const float*)d_in[9];
  const float* h0_ab   = (const float*)d_in[10];
  const float* h1_intw = (const float*)d_in[11];
  const float* h1_sw   = (const float*)d_in[12];
  const float* h1_sb   = (const float*)d_in[13];
  const float* h1_aw   = (const float*)d_in[14];
  const float* h1_ab   = (const float*)d_in[15];
  const float* W_intw  = (const float*)d_in[16];
  const float* W_sw    = (const float*)d_in[17];
  const float* W_sb    = (const float*)d_in[18];
  const float* pw0     = (const float*)d_in[19];
  const float* pw1     = (const float*)d_in[20];
  const float* pb1     = (const float*)d_in[21];
  float* outp = (float*)d_out;

  float* w = (float*)d_ws;
  float* invd = w;  w += NP;
  float* cut  = w;  w += NP;
  float* indf = w;  w += NA*5;
  float* proj0= w;  w += NA;
  float* xt   = w;  w += NA*20;
  float* hA   = w;  w += NA*20;
  float* hB   = w;  w += NA*20;
  float* ct   = w;  w += NA*20;
  float* x0   = w;  w += NA;
  float* WtF  = w;  w += 80*800;
  float* WsT  = w;  w += 80*40;

  k_setup<<<512,256,0,stream>>>(pf,ps,species,coord,xh,pw0,pb1,W_intw,W_sw,
                                invd,cut,indf,proj0,WtF,WsT);
  k_f0<<<1024,256,0,stream>>>(ps,invd,cut,indf,h0_intw,h0_sw,h0_sb,h0_aw,h0_ab,
                              ct,hA);

  const float* hin = hA; float* ho = hB;
  for(int step=0; step<5; ++step){
    int use_raw = (step<2)?1:0;
    int col = (step<2)? step : 0;
    k_xt<<<512,256,0,stream>>>(ps,invd,cut,xraw,x0,use_raw,col,
                               h1_intw,h1_sw,h1_sb,h1_aw,h1_ab, xt);
    int out_col = (step>=2)? (step-2) : -1;
    k_envlstm<<<256,320,0,stream>>>(ps,invd,cut,xt,hin,WtF,WsT,W_sb,pw1,proj0,
                                    ct, ho, x0, outp, out_col);
    const float* tswap = hin; hin = ho; ho = (float*)tswap;
  }
}

// Round 4
// 134.476 us; speedup vs baseline: 5.3945x; 5.3945x over previous
//
#include <hip/hip_runtime.h>
#include <hip/hip_bf16.h>

// Round 4: optimize k_envlstm (was 5x139us = 96% of runtime, latency-bound:
// VALUBusy 9.5%, occupancy 14%).
//  - P1: stage molecule's 128x40 x/h rows in LDS once (removes 20x redundant
//    global gathers); sense values precomputed to LDS; env accumulated by
//    (atom, f-pair) threads (VALU-bound).
//  - P2: K=864 GEMM (env(800) + self(40) + pad(24), bias folded) via
//    mfma_f32_16x16x32_bf16. env packed bf16 in LDS in A-fragment order;
//    W pre-arranged in k_setup into B-fragment order (coalesced b128 global).
//  - 512-thread blocks (8 waves), 256 blocks, LDS 62KB union.

#define DEG 32
#define NA 4096
#define NP 131072

typedef __hip_bfloat16 bf16;
typedef __attribute__((ext_vector_type(8))) short short8v;
typedef __attribute__((ext_vector_type(4))) float f32x4;

__device__ __forceinline__ float sigmoidf_(float x){ return 1.f/(1.f+expf(-x)); }
__device__ __forceinline__ float softplusf_(float x){ return fmaxf(x,0.f) + log1pf(expf(-fabsf(x))); }
// mu_s = linspace(1/5, 1/0.7, 20); sigma = (1/0.7-1/5)/20
__device__ __forceinline__ float senseval(float ivd, float cu, int s){
  float mu = 0.2f + (float)s * 0.06466165413533835f;
  float z  = (ivd - mu) * 16.27906976744186f;
  return expf(-0.5f*z*z) * cu;
}
// pack two f32 -> u32 holding two bf16 (RTNE), lo in bits 0..15
__device__ __forceinline__ unsigned bf16pack(float lo, float hi){
  unsigned ul = __float_as_uint(lo), uh = __float_as_uint(hi);
  unsigned rl = (ul + 0x7fffu + ((ul>>16)&1u)) >> 16;
  unsigned rh = (uh + 0x7fffu + ((uh>>16)&1u)) & 0xffff0000u;
  return rl | rh;
}

// ---------------- setup: pair geometry, encodings, W -> MFMA B-frag layout ---
// Wmf[((slab*5+gt)*64+l)*8+j] = Wext[k][g], k=slab*32+(l>>4)*8+j, g=gt*16+(l&15)
// Wext rows: k<800 -> Wint[k][g]; 800<=k<840 -> Wself[k-800][g]; else 0.
__global__ __launch_bounds__(256) void k_setup(
    const int* __restrict__ pf, const int* __restrict__ ps,
    const int* __restrict__ species,
    const float* __restrict__ coord, const float* __restrict__ xh,
    const float* __restrict__ pw0, const float* __restrict__ pb1,
    const float* __restrict__ Wint, const float* __restrict__ Wself,
    float* __restrict__ invd, float* __restrict__ cut,
    float* __restrict__ indf, float* __restrict__ proj0,
    bf16* __restrict__ Wmf)
{
  int tid = blockIdx.x*256 + threadIdx.x;
  if (tid < NP){
    int i = pf[tid], j = ps[tid];
    float dx = coord[i*3+0]-coord[j*3+0];
    float dy = coord[i*3+1]-coord[j*3+1];
    float dz = coord[i*3+2]-coord[j*3+2];
    float d = sqrtf(dx*dx+dy*dy+dz*dz + 1e-12f);
    invd[tid] = 1.f/d;
    float cu = 0.f;
    if (d < 7.5f){ float c = cosf(d * 0.20943951023931953f); cu = c*c; } // pi/15
    cut[tid] = cu;
  }
  if (tid < NA){
    int sp = species[tid];
    float f0 = (sp==1)?1.f:0.f, f1 = (sp==8)?1.f:0.f;
    float f2=xh[tid*3+0], f3=xh[tid*3+1], f4=xh[tid*3+2];
    indf[tid*5+0]=f0; indf[tid*5+1]=f1; indf[tid*5+2]=f2; indf[tid*5+3]=f3; indf[tid*5+4]=f4;
    proj0[tid] = pb1[0] + f0*pw0[0] + f1*pw0[1] + f2*pw0[2] + f3*pw0[3] + f4*pw0[4];
  }
  if (tid < 69120){
    int j = tid & 7, l = (tid>>3) & 63, gt = (tid>>9)%5, slab = tid/2560;
    int k = slab*32 + ((l>>4)<<3) + j;
    int g = gt*16 + (l&15);
    float v = 0.f;
    if (k < 800)      v = Wint[k*80+g];
    else if (k < 840) v = Wself[(k-800)*80+g];
    Wmf[tid] = __float2bfloat16(v);
  }
}

// ---------------- f0 = hipnn(ind_f) -> c_t, h_t (unchanged, verified) --------
__global__ __launch_bounds__(256) void k_f0(
    const int* __restrict__ ps,
    const float* __restrict__ invd, const float* __restrict__ cut,
    const float* __restrict__ indf,
    const float* __restrict__ intw, const float* __restrict__ selfw,
    const float* __restrict__ selfb,
    const float* __restrict__ aw, const float* __restrict__ ab,
    float* __restrict__ ct, float* __restrict__ hout)
{
  __shared__ float xn[4][160];
  __shared__ float env[4][100];
  __shared__ float ya[4][40];
  __shared__ float yb[4][40];
  int a_loc = threadIdx.x>>6, slot = threadIdx.x&63;
  int atom = blockIdx.x*4 + a_loc;
  int p0 = atom*DEG;
  for(int idx=slot; idx<160; idx+=64){
    int k = idx/5, f = idx%5;
    int n = ps[p0+k];
    xn[a_loc][idx] = indf[n*5+f];
  }
  __syncthreads();
  for(int e=slot; e<100; e+=64){
    int s = e/5, f = e%5;
    float acc=0.f;
    for(int k=0;k<DEG;k++){
      float sv = senseval(invd[p0+k], cut[p0+k], s);
      acc += sv * xn[a_loc][k*5+f];
    }
    env[a_loc][e]=acc;
  }
  __syncthreads();
  if (slot < 40){
    int o = slot;
    float acc = selfb[o];
    #pragma unroll
    for(int f=0;f<5;f++) acc += indf[atom*5+f]*selfw[f*40+o];
    for(int e=0;e<100;e++) acc += env[a_loc][e]*intw[e*40+o];
    ya[a_loc][o] = softplusf_(acc);
  }
  __syncthreads();
  float* cur = ya[a_loc]; float* nxt = yb[a_loc];
  for(int l=0;l<3;l++){
    if (slot<40){
      int o=slot;
      float acc = ab[l*40+o];
      for(int f=0;f<40;f++) acc += cur[f]*aw[l*1600+f*40+o];
      nxt[o] = softplusf_(acc);
    }
    __syncthreads();
    float* t=cur; cur=nxt; nxt=t;
  }
  if (slot<20){
    ct[atom*20+slot]   = cur[slot];
    hout[atom*20+slot] = cur[20+slot];
  }
}

// ---------------- x_t = hipnn_h1(x_in) (unchanged, verified) -----------------
__global__ __launch_bounds__(256) void k_xt(
    const int* __restrict__ ps,
    const float* __restrict__ invd, const float* __restrict__ cut,
    const float* __restrict__ xraw, const float* __restrict__ x0,
    int use_raw, int col,
    const float* __restrict__ intw, const float* __restrict__ selfw,
    const float* __restrict__ selfb,
    const float* __restrict__ aw, const float* __restrict__ ab,
    float* __restrict__ xt)
{
  __shared__ float xv[8][32];
  __shared__ float env1[8][20];
  __shared__ float ya[8][20];
  __shared__ float yb[8][20];
  int a_loc = threadIdx.x>>5, slot = threadIdx.x&31;
  int atom = blockIdx.x*8 + a_loc;
  int p0 = atom*DEG;
  {
    int n = ps[p0+slot];
    xv[a_loc][slot] = use_raw ? xraw[n*2+col] : x0[n];
  }
  __syncthreads();
  if (slot<20){
    int s=slot; float acc=0.f;
    for(int k=0;k<DEG;k++) acc += senseval(invd[p0+k],cut[p0+k],s) * xv[a_loc][k];
    env1[a_loc][s]=acc;
  }
  __syncthreads();
  if (slot<20){
    int o=slot;
    float xs = use_raw ? xraw[atom*2+col] : x0[atom];
    float acc = selfb[o] + xs*selfw[o];
    #pragma unroll
    for(int s=0;s<20;s++) acc += env1[a_loc][s]*intw[s*20+o];
    ya[a_loc][o]=softplusf_(acc);
  }
  __syncthreads();
  float* cur = ya[a_loc]; float* nxt = yb[a_loc];
  for(int l=0;l<3;l++){
    if(slot<20){
      int o=slot;
      float acc = ab[l*20+o];
      #pragma unroll
      for(int f=0;f<20;f++) acc += cur[f]*aw[l*400+f*20+o];
      nxt[o]=softplusf_(acc);
    }
    __syncthreads();
    float* t=cur;cur=nxt;nxt=t;
  }
  if(slot<20) xt[atom*20+slot]=cur[slot];
}

// ---------------- env + GEMM(MFMA) + LSTM, v3 --------------------------------
// Block: 16 atoms, 512 threads, one molecule-slice. LDS union 62KB.
__global__ __launch_bounds__(512) void k_envlstm(
    const int* __restrict__ ps,
    const float* __restrict__ invd, const float* __restrict__ cut,
    const float* __restrict__ xt, const float* __restrict__ hin,
    const bf16* __restrict__ Wmf, const float* __restrict__ Wb,
    const float* __restrict__ pw1, const float* __restrict__ proj0,
    float* __restrict__ ct, float* __restrict__ hout, float* __restrict__ x0,
    float* __restrict__ outp, int out_col)
{
  __shared__ float smem[15488];                 // 61,952 B
  float* xh_s   = smem;                         // [128][40] f32 (phases 0-1)
  float* sv_s   = smem + 5120;                  // [16][648]: [a][kn*20+s] (ph 0-1)
  unsigned* env_p = (unsigned*)smem;            // [16][436] u32 bf16-pairs (ph 2-3)
  float* tmp_s  = smem + 7040;                  // [16][80] (ph 3-4)
  float* red_s  = smem + 8320;                  // [16][20] (ph 4)

  const int t    = threadIdx.x;
  const int blk  = blockIdx.x;
  const int abase = blk * 16;                   // first atom of block
  const int nbase = (blk >> 3) * 128;           // molecule atom base

  // ---- ph0: t<320: sense values to LDS; t>=320: stage x/h rows of molecule
  if (t < 320){
    int a = t/20, s = t%20;
    int p0 = (abase + a)*DEG;
    float* svrow = sv_s + a*648;
    for(int k=0;k<DEG;k++){
      svrow[k*20+s] = senseval(invd[p0+k], cut[p0+k], s);
    }
  } else {
    for(int i = t-320; i < 5120; i += 192){
      int r = i/40, f = i%40;
      int ga = nbase + r;
      xh_s[i] = (f<20) ? xt[ga*20+f] : hin[ga*20+(f-20)];
    }
  }
  __syncthreads();

  // ---- ph1: env accumulate; thread = (a, f2), acc[s][2] over 20 s
  float acc[20][2];
  float selfp0 = 0.f, selfp1 = 0.f;
  if (t < 320){
    int a = t/20, f2 = t%20;
    int atom = abase + a;
    #pragma unroll
    for(int s=0;s<20;s++){ acc[s][0]=0.f; acc[s][1]=0.f; }
    const float* svrow = sv_s + a*648;
    const int* psrow = ps + atom*DEG;
    for(int k=0;k<DEG;k++){
      int nl = psrow[k] - nbase;
      float2 ft = *(const float2*)(xh_s + nl*40 + f2*2);
      const float4* sq = (const float4*)(svrow + k*20);
      float4 q0=sq[0], q1=sq[1], q2=sq[2], q3=sq[3], q4=sq[4];
      float svv[20] = {q0.x,q0.y,q0.z,q0.w, q1.x,q1.y,q1.z,q1.w,
                       q2.x,q2.y,q2.z,q2.w, q3.x,q3.y,q3.z,q3.w,
                       q4.x,q4.y,q4.z,q4.w};
      #pragma unroll
      for(int s=0;s<20;s++){ acc[s][0] += svv[s]*ft.x; acc[s][1] += svv[s]*ft.y; }
    }
    int own = (blk & 7)*16 + a;                // own atom's local row
    selfp0 = xh_s[own*40 + f2*2];
    selfp1 = xh_s[own*40 + f2*2 + 1];
  }
  __syncthreads();

  // ---- ph2: write env_p (bf16 pairs): k = s*40 + f; self-ext k=800+f; pad 0
  if (t < 320){
    int a = t/20, f2 = t%20;
    unsigned* er = env_p + a*436;
    #pragma unroll
    for(int s=0;s<20;s++) er[s*20+f2] = bf16pack(acc[s][0], acc[s][1]);
    er[400+f2] = bf16pack(selfp0, selfp1);
    if (f2 < 12) er[420+f2] = 0u;
  }
  __syncthreads();

  // ---- ph3: MFMA GEMM: waves 0..4 each own one 16-wide g-tile; K=864=27 slabs
  if (t < 320){
    int wv = t >> 6, l = t & 63;
    f32x4 cacc = {0.f,0.f,0.f,0.f};
    const unsigned* abase_p = env_p + (l & 15)*436 + ((l>>4)<<2);
    const short8v* bptr = (const short8v*)Wmf + (wv*64 + l);
    #pragma unroll 3
    for(int slab=0; slab<27; ++slab){
      short8v av = *(const short8v*)(abase_p + slab*16);
      short8v bv = bptr[slab*320];
      cacc = __builtin_amdgcn_mfma_f32_16x16x32_bf16(av, bv, cacc, 0,0,0);
    }
    int g = wv*16 + (l & 15);
    float wb = Wb[g];
    int r0 = (l>>4)*4;
    #pragma unroll
    for(int r=0;r<4;r++) tmp_s[(r0+r)*80 + g] = cacc[r] + wb;
  }
  __syncthreads();

  // ---- ph4: LSTM gates + h/c update + output projection
  if (t < 320){
    int a = t/20, u = t%20;
    int atom = abase + a;
    float4 tv = *(const float4*)(tmp_s + a*80 + u*4);
    float cold = ct[atom*20+u];
    float cnew = sigmoidf_(tv.y)*cold + sigmoidf_(tv.x)*tanhf(tv.z);
    float og   = sigmoidf_(tv.w);
    ct[atom*20+u]   = cnew;
    hout[atom*20+u] = og*tanhf(cnew);
    red_s[a*20+u]   = og*pw1[u];
  }
  __syncthreads();
  if (t < 320 && (t%20)==0){
    int a = t/20, atom = abase + a;
    float accx = proj0[atom];
    #pragma unroll
    for(int u=0;u<20;u++) accx += red_s[a*20+u];
    x0[atom] = accx;
    if(out_col>=0) outp[atom*3+out_col] = accx;
  }
}

extern "C" void kernel_launch(void* const* d_in, const int* in_sizes, int n_in,
                              void* d_out, int out_size, void* d_ws, size_t ws_size,
                              hipStream_t stream)
{
  const int*   species = (const int*)  d_in[0];
  const float* coord   = (const float*)d_in[1];
  const float* xh      = (const float*)d_in[2];
  const float* xraw    = (const float*)d_in[3];
  const int*   pf      = (const int*)  d_in[4];
  const int*   ps      = (const int*)  d_in[5];
  const float* h0_intw = (const float*)d_in[6];
  const float* h0_sw   = (const float*)d_in[7];
  const float* h0_sb   = (const float*)d_in[8];
  const float* h0_aw   = (const float*)d_in[9];
  const float* h0_ab   = (const float*)d_in[10];
  const float* h1_intw = (const float*)d_in[11];
  const float* h1_sw   = (const float*)d_in[12];
  const float* h1_sb   = (const float*)d_in[13];
  const float* h1_aw   = (const float*)d_in[14];
  const float* h1_ab   = (const float*)d_in[15];
  const float* W_intw  = (const float*)d_in[16];
  const float* W_sw    = (const float*)d_in[17];
  const float* W_sb    = (const float*)d_in[18];
  const float* pw0     = (const float*)d_in[19];
  const float* pw1     = (const float*)d_in[20];
  const float* pb1     = (const float*)d_in[21];
  float* outp = (float*)d_out;

  float* w = (float*)d_ws;
  float* invd = w;  w += NP;
  float* cut  = w;  w += NP;
  float* indf = w;  w += NA*5;
  float* proj0= w;  w += NA;
  float* xt   = w;  w += NA*20;
  float* hA   = w;  w += NA*20;
  float* hB   = w;  w += NA*20;
  float* ct   = w;  w += NA*20;
  float* x0   = w;  w += NA;
  bf16*  Wmf  = (bf16*)w;              // 69120 bf16 (16B-aligned)

  k_setup<<<512,256,0,stream>>>(pf,ps,species,coord,xh,pw0,pb1,W_intw,W_sw,
                                invd,cut,indf,proj0,Wmf);
  k_f0<<<1024,256,0,stream>>>(ps,invd,cut,indf,h0_intw,h0_sw,h0_sb,h0_aw,h0_ab,
                              ct,hA);

  const float* hin = hA; float* ho = hB;
  for(int step=0; step<5; ++step){
    int use_raw = (step<2)?1:0;
    int col = (step<2)? step : 0;
    k_xt<<<512,256,0,stream>>>(ps,invd,cut,xraw,x0,use_raw,col,
                               h1_intw,h1_sw,h1_sb,h1_aw,h1_ab, xt);
    int out_col = (step>=2)? (step-2) : -1;
    k_envlstm<<<256,512,0,stream>>>(ps,invd,cut,xt,hin,Wmf,W_sb,pw1,proj0,
                                    ct, ho, x0, outp, out_col);
    const float* tswap = hin; hin = ho; ho = (float*)tswap;
  }
}